// Round 14
// baseline (181.886 us; speedup 1.0000x reference)
//
#include <hip/hip_runtime.h>
#include <hip/hip_bf16.h>
#include <math.h>
#include <stdint.h>

#define N_TOKENS 16384
#define DIM 4096
#define NEXP 64

typedef const __attribute__((address_space(1))) void gvoid_t;
typedef __attribute__((address_space(3))) void svoid_t;
typedef short bf16x8 __attribute__((ext_vector_type(8)));
typedef float f32x4 __attribute__((ext_vector_type(4)));

constexpr int TOK_BLK = 16;  // tokens per block -> grid 1024 = 4 blocks/CU

__device__ __forceinline__ unsigned short bf16_rn(float f) {
  unsigned u = __float_as_uint(f);
  u += 0x7fffu + ((u >> 16) & 1u);
  return (unsigned short)(u >> 16);
}
__device__ __forceinline__ float bf16_tof(unsigned short h) {
  return __uint_as_float(((unsigned)h) << 16);
}

// packed hi/lo split: 8 floats -> bf16x8 hi + bf16x8 lo via v_cvt_pk_bf16_f32
__device__ __forceinline__ void split8(const float4 a, const float4 b,
                                       bf16x8& hi, bf16x8& lo) {
  const float f[8] = {a.x, a.y, a.z, a.w, b.x, b.y, b.z, b.w};
  union { unsigned u[4]; bf16x8 v; } H, L;
#pragma unroll
  for (int p = 0; p < 4; ++p) {
    const float2 fp = make_float2(f[2 * p], f[2 * p + 1]);
    const __hip_bfloat162 hh = __float22bfloat162_rn(fp);
    const unsigned uh = *(const unsigned*)&hh;
    const float h0 = __uint_as_float(uh << 16);
    const float h1 = __uint_as_float(uh & 0xffff0000u);
    const __hip_bfloat162 ll =
        __float22bfloat162_rn(make_float2(fp.x - h0, fp.y - h1));
    H.u[p] = uh;
    L.u[p] = *(const unsigned*)&ll;
  }
  hi = H.v;
  lo = L.v;
}

// ------ K0: split W into bf16 hi + lo (1 MB, once) + zero cnt (no memset) ------
__global__ __launch_bounds__(256) void k0_wsplit(const float* __restrict__ W,
                                                 unsigned short* __restrict__ hi,
                                                 unsigned short* __restrict__ lo,
                                                 int* __restrict__ cnt) {
  const int i = (blockIdx.x * 256 + threadIdx.x) * 4;
  const float4 f = *(const float4*)(W + i);
  ushort4 h, l;
  h.x = bf16_rn(f.x); l.x = bf16_rn(f.x - bf16_tof(h.x));
  h.y = bf16_rn(f.y); l.y = bf16_rn(f.y - bf16_tof(h.y));
  h.z = bf16_rn(f.z); l.z = bf16_rn(f.z - bf16_tof(h.z));
  h.w = bf16_rn(f.w); l.w = bf16_rn(f.w - bf16_tof(h.w));
  *(ushort4*)(hi + i) = h;
  *(ushort4*)(lo + i) = l;
  if (blockIdx.x < 8) {  // zero cnt[64][128] (runs before k1 in-stream)
    int4* c4 = (int4*)cnt;
    c4[blockIdx.x * 256 + threadIdx.x] = make_int4(0, 0, 0, 0);
  }
}

// ------- K1 (fused, MFMA): logits + softmax + top2 + sel + histogram ----------
// Double-bf16 GEMM (xhi@Whi + xlo@Whi + xhi@Wlo; lo*lo dropped ~2e-6).
// R13 residuals fixed: (1) scalar bf16 split (~160 VALU/chunk) -> packed
// cvt_pk path (~48); (2) 2 blocks/CU -> TOK_BLK=16, grid 1024 = 4 blocks/CU
// (LDS 33KB: W dbuf 32KB, lg overlays wh after the K-loop).
// Wave = 16 tokens x one 16-expert N-tile (nt = wid). MFMA 16x16x32_bf16,
// layouts m89-verified (R12/13 passed):
//   A row=lane&15 (token), k=(lane>>4)*8+j; B col=lane&15 (expert);
//   D col=lane&15 (expert), row=(lane>>4)*4+reg (token).
__global__ __launch_bounds__(256, 4) void k1_fused(
    const float* __restrict__ x, const unsigned short* __restrict__ Whi,
    const unsigned short* __restrict__ Wlo, float* __restrict__ topw,
    int* __restrict__ sel, int* __restrict__ cnt) {
  __shared__ __align__(16) unsigned char smem[32768 + 256];
  unsigned short* const wh0 = (unsigned short*)smem;            // 8 KB
  unsigned short* const wh1 = (unsigned short*)(smem + 8192);   // 8 KB
  unsigned short* const wl0 = (unsigned short*)(smem + 16384);  // 8 KB
  unsigned short* const wl1 = (unsigned short*)(smem + 24576);  // 8 KB
  float* const lg = (float*)smem;            // overlay after K-loop (4.3 KB)
  int* const hist = (int*)(smem + 32768);    // 256 B

  const int tid = threadIdx.x;
  const int lane = tid & 63;
  const int wid = __builtin_amdgcn_readfirstlane(tid >> 6);  // wave = N-tile
  const int r = lane & 15;  // A token row / B expert col within tile
  const int g = lane >> 4;  // k-group
  const int tok0 = blockIdx.x * TOK_BLK;

  f32x4 acc = {};  // one N-tile

  // stage Whi/Wlo[0..63][kc..+63] (bf16): 2+2 glds/wave (1KB: 8 rows x 8 slots)
  auto stage_w = [&](unsigned short* hd, unsigned short* ld, int kc) {
#pragma unroll
    for (int q = 0; q < 2; ++q) {
      const int r0 = wid * 16 + q * 8;  // wave-uniform row base
      const int row = r0 + (lane >> 3);
      const int s = (lane & 7) ^ (row & 7);  // rule-21 source-side involution
      __builtin_amdgcn_global_load_lds(
          (gvoid_t*)(Whi + (size_t)row * DIM + kc + 8 * s),
          (svoid_t*)(hd + r0 * 64), 16, 0, 0);
      __builtin_amdgcn_global_load_lds(
          (gvoid_t*)(Wlo + (size_t)row * DIM + kc + 8 * s),
          (svoid_t*)(ld + r0 * 64), 16, 0, 0);
    }
  };

  // this lane's x row base (A-slice at +t*64 + h*32 + g*8)
  const float* xrow = x + (size_t)(tok0 + r) * DIM + g * 8;
  auto xload = [&](float4* xd, int t) {
    const float* p = xrow + t * 64;
    xd[0] = *(const float4*)(p);
    xd[1] = *(const float4*)(p + 4);
    xd[2] = *(const float4*)(p + 32);
    xd[3] = *(const float4*)(p + 36);
  };

  auto body = [&](int t, float4* xc, float4* xn, unsigned short* whc,
                  unsigned short* wlc, unsigned short* whn, unsigned short* wln) {
    if (t + 1 < 64) {
      xload(xn, t + 1);  // x prefetch -> regs (T14)
      stage_w(whn, wln, (t + 1) * 64);
    }
#pragma unroll
    for (int h = 0; h < 2; ++h) {  // two K=32 MFMA steps per 64-k chunk
      bf16x8 Ahi, Alo;
      split8(xc[2 * h], xc[2 * h + 1], Ahi, Alo);
      const int ws = h * 4 + g;  // logical 16B slot within W row
      const int wrow = wid * 16 + r;
      const int wadr = wrow * 64 + 8 * (ws ^ (wrow & 7));
      const bf16x8 Bhi = *(const bf16x8*)(whc + wadr);
      const bf16x8 Blo = *(const bf16x8*)(wlc + wadr);
      acc = __builtin_amdgcn_mfma_f32_16x16x32_bf16(Ahi, Bhi, acc, 0, 0, 0);
      acc = __builtin_amdgcn_mfma_f32_16x16x32_bf16(Alo, Bhi, acc, 0, 0, 0);
      acc = __builtin_amdgcn_mfma_f32_16x16x32_bf16(Ahi, Blo, acc, 0, 0, 0);
    }
    __syncthreads();  // drains glds + x prefetch; closes buffer reuse
  };

  float4 xA[4], xB[4];
  xload(xA, 0);
  stage_w(wh0, wl0, 0);
  __syncthreads();

  for (int tt = 0; tt < 64; tt += 2) {
    body(tt, xA, xB, wh0, wl0, wh1, wl1);
    body(tt + 1, xB, xA, wh1, wl1, wh0, wl0);
  }

  // epilogue: lg overlays wh (all waves are past the last W read)
  if (tid < NEXP) hist[tid] = 0;
  // D: token = g*4+rg, expert = wid*16+r
#pragma unroll
  for (int rg = 0; rg < 4; ++rg)
    lg[(g * 4 + rg) * 68 + wid * 16 + r] = acc[rg];
  __syncthreads();

  // softmax + top2 per token (threads 0..15), then histogram
  if (tid < TOK_BLK) {
    const float* rowp = lg + tid * 68;
    float4 v[16];
#pragma unroll
    for (int c = 0; c < 16; ++c) v[c] = *(const float4*)(rowp + c * 4);

    float v0 = -INFINITY, v1 = -INFINITY;
    int i0 = 0, i1 = 0;
#define TOP2_STEP(val, idx)                                  \
  {                                                          \
    const float vv = (val);                                  \
    const int ee = (idx);                                    \
    if (vv > v0) { v1 = v0; i1 = i0; v0 = vv; i0 = ee; }     \
    else if (vv > v1) { v1 = vv; i1 = ee; }                  \
  }
#pragma unroll
    for (int c = 0; c < 16; ++c) {
      TOP2_STEP(v[c].x, c * 4 + 0);
      TOP2_STEP(v[c].y, c * 4 + 1);
      TOP2_STEP(v[c].z, c * 4 + 2);
      TOP2_STEP(v[c].w, c * 4 + 3);
    }
#undef TOP2_STEP

    float denom = 0.f;
#pragma unroll
    for (int c = 0; c < 16; ++c) {
      denom += expf(v[c].x - v0);
      denom += expf(v[c].y - v0);
      denom += expf(v[c].z - v0);
      denom += expf(v[c].w - v0);
    }
    const float w0 = 1.0f / denom;  // expf(0)==1 exactly
    const float w1 = expf(v1 - v0) / denom;

    const int tk = tok0 + tid;
    topw[2 * tk + 0] = w0;
    topw[2 * tk + 1] = w1;
    sel[2 * tk + 0] = i0;
    sel[2 * tk + 1] = i1;
    atomicAdd(&hist[i0], 1);
    atomicAdd(&hist[i1], 1);
  }
  __syncthreads();
  if (tid < NEXP) {
    const int h = hist[tid];
    if (h) atomicAdd(&cnt[tid * 128 + (blockIdx.x >> 3)], h);  // cnt[e][chunk]
  }
}

// -------- K3: expert totals (counts out), exclusive offsets, chunk bases --------
__global__ void k3_scan(const int* __restrict__ cnt, int* __restrict__ cb,
                        float* __restrict__ counts_out) {
  __shared__ int tot[NEXP];
  const int e = threadIdx.x;  // 64 threads
  const int4* row4 = (const int4*)(cnt + e * 128);
  int run = 0;
#pragma unroll
  for (int q = 0; q < 32; ++q) {
    const int4 v = row4[q];
    run += v.x + v.y + v.z + v.w;
  }
  tot[e] = run;
  counts_out[e] = (float)run;
  __syncthreads();
  int g = 0;
  for (int q = 0; q < e; ++q) g += tot[q];
  int r = g;
  for (int p = 0; p < 128; ++p) {
    cb[p * NEXP + e] = r;
    r += cnt[e * 128 + p];
  }
}

// ---------------- K4: stable scatter (counting-sort permutation) ----------------
__global__ __launch_bounds__(256) void k4_scatter(const int* __restrict__ sel,
                                                  const int* __restrict__ cb,
                                                  float* __restrict__ gout) {
  __shared__ int wcnt[4 * NEXP];
  const int tid = threadIdx.x;
  const int s = blockIdx.x * 256 + tid;
  const int e = sel[s];
  const int lane = tid & 63;
  const int wv = tid >> 6;
  wcnt[tid] = 0;
  __syncthreads();

  unsigned long long mask = ~0ull;
#pragma unroll
  for (int b = 0; b < 6; ++b) {
    const unsigned long long bb = __ballot((e >> b) & 1);
    mask &= ((e >> b) & 1) ? bb : ~bb;
  }
  const unsigned long long below = mask & ((1ull << lane) - 1ull);
  const int wr = __popcll(below);
  if (wr == 0) wcnt[wv * NEXP + e] = __popcll(mask);
  __syncthreads();

  int base = cb[blockIdx.x * NEXP + e];
  for (int w2 = 0; w2 < wv; ++w2) base += wcnt[w2 * NEXP + e];
  gout[base + wr] = (float)s;
}

extern "C" void kernel_launch(void* const* d_in, const int* in_sizes, int n_in,
                              void* d_out, int out_size, void* d_ws, size_t ws_size,
                              hipStream_t stream) {
  const float* x = (const float*)d_in[0];
  const float* W = (const float*)d_in[1];
  float* out = (float*)d_out;

  unsigned short* whi_g = (unsigned short*)d_ws;  // 512 KB
  unsigned short* wlo_g = whi_g + NEXP * DIM;     // 512 KB
  int* sel = (int*)(wlo_g + NEXP * DIM);          // 128 KB
  int* cnt = sel + N_TOKENS * 2;                  // 32 KB (cnt[e][128])
  int* cb = cnt + 128 * NEXP;                     // 32 KB (cb[p][e])

  hipLaunchKernelGGL(k0_wsplit, dim3((NEXP * DIM) / 1024), dim3(256), 0, stream,
                     W, whi_g, wlo_g, cnt);
  hipLaunchKernelGGL(k1_fused, dim3(N_TOKENS / TOK_BLK), dim3(256), 0, stream,
                     x, whi_g, wlo_g, out, sel, cnt);
  hipLaunchKernelGGL(k3_scan, dim3(1), dim3(64), 0, stream, cnt, cb,
                     out + 2 * N_TOKENS + 2 * N_TOKENS);
  hipLaunchKernelGGL(k4_scatter, dim3((2 * N_TOKENS) / 256), dim3(256), 0, stream,
                     sel, cb, out + 2 * N_TOKENS);
}